// Round 1
// baseline (266.511 us; speedup 1.0000x reference)
//
#include <hip/hip_runtime.h>
#include <hip/hip_bf16.h>

// GraphEmbedder: B=8, C=64, G=65536, 4 layers of y=lrelu(W@[x; x-x0]), then max over G.
// Identity: W@[x; x-x0] = Wa@x - Wb@x0  with Wa = W[:,:64]+W[:,64:], Wb = W[:,64:].
// x0 chains per batch: x0^{l+1} = lrelu(W_l[:,:64]@x0^l)  -> exact fp32 in prep kernel.
// Main compute: f16 MFMA 16x16x16; D-layout == next-layer B-layout (same lane/reg),
// so the whole 4-layer chain is register-resident per wave.

#define G_TOT 65536
#define NB 8

typedef _Float16 half4 __attribute__((ext_vector_type(4)));
typedef float float4_ __attribute__((ext_vector_type(4)));

// ws layout (floats):
//   [0, 16384)      Wa[l][o][c] fp32   (4*64*64)
//   [16384, 18432)  bias[l][b][o] fp32 (4*8*64)
//   [18432, 18944)  maxenc (uint32, ordered-float encoding), zeroed by prep

__global__ __launch_bounds__(512) void ge_prep(
    const float* __restrict__ feat,
    const float* __restrict__ W0, const float* __restrict__ W1,
    const float* __restrict__ W2, const float* __restrict__ W3,
    float* __restrict__ ws)
{
    const int tid = threadIdx.x;
    // zero the atomic-max area (re-poisoned to 0xAA before every timed call)
    unsigned* maxenc = (unsigned*)(ws + 18432);
    if (tid < 512) maxenc[tid] = 0u;   // encodes "-NaN" sentinel, loses to everything

    // Wa = W[:,:64] + W[:,64:]
    for (int i = tid; i < 4 * 64 * 64; i += 512) {
        int l = i >> 12, o = (i >> 6) & 63, c = i & 63;
        const float* Wl = (l == 0) ? W0 : (l == 1) ? W1 : (l == 2) ? W2 : W3;
        ws[i] = Wl[o * 128 + c] + Wl[o * 128 + 64 + c];
    }

    // exact fp32 bias chain: bias[l][b][o] = sum_c W_l[o][64+c] * x0^l[b][c]
    __shared__ float xA[NB][64];
    __shared__ float xB[NB][64];
    {
        int b = tid >> 6, c = tid & 63;           // 512 threads = 8*64
        xA[b][c] = feat[(size_t)(b * 64 + c) * G_TOT];   // g = 0 column
    }
    __syncthreads();
    float* bias = ws + 16384;
    for (int l = 0; l < 4; ++l) {
        const float* Wl = (l == 0) ? W0 : (l == 1) ? W1 : (l == 2) ? W2 : W3;
        const float* src = (l & 1) ? &xB[0][0] : &xA[0][0];
        float*       dst = (l & 1) ? &xA[0][0] : &xB[0][0];
        int b = tid >> 6, o = tid & 63;
        float s1 = 0.f, s2 = 0.f;
        for (int c = 0; c < 64; ++c) {
            float xv = src[b * 64 + c];
            s1 += Wl[o * 128 + c] * xv;        // W[:,:64] @ x0  -> next x0
            s2 += Wl[o * 128 + 64 + c] * xv;   // W[:,64:] @ x0  -> bias
        }
        bias[l * 512 + b * 64 + o] = s2;
        dst[b * 64 + o] = fmaxf(s1, 0.1f * s1);  // leaky_relu
        __syncthreads();
    }
}

__global__ __launch_bounds__(256, 2) void ge_main(
    const float* __restrict__ feat,
    const float* __restrict__ ws_wa,
    const float* __restrict__ ws_bias,
    unsigned* __restrict__ maxenc)
{
    // weights as f16 in LDS; row stride 68 halves -> 8B-aligned ds_read_b64
    __shared__ _Float16 lwa[4 * 64 * 68];
    __shared__ float blockmax[4][64];
    const int tid = threadIdx.x;

    for (int i = tid; i < 4 * 64 * 64; i += 256) {
        int l = i >> 12, o = (i >> 6) & 63, c = i & 63;
        lwa[(l * 64 + o) * 68 + c] = (_Float16)ws_wa[i];
    }
    __syncthreads();

    const int w = tid >> 6, lane = tid & 63;
    const int q = lane >> 4, n = lane & 15;
    const int b  = blockIdx.x >> 8;                       // 8 batches
    const int g0 = ((blockIdx.x & 255) << 8) + (w << 6);  // 256 cols/block, 64/wave

    const float* Xb    = feat + (size_t)b * 64 * G_TOT;
    const float* biasb = ws_bias + b * 64;

    float rmax[4][4];
#pragma unroll
    for (int mt = 0; mt < 4; ++mt)
#pragma unroll
        for (int j = 0; j < 4; ++j) rmax[mt][j] = -__builtin_inff();

#pragma unroll 1
    for (int nt = 0; nt < 4; ++nt) {
        const int gcol = g0 + (nt << 4) + n;

        // layer-1 B fragments straight from global (B[k][n]: n=lane&15, k=4q+j in chunk kf)
        half4 bf[4];
#pragma unroll
        for (int kf = 0; kf < 4; ++kf) {
            int kbase = (kf << 4) + (q << 2);
            float x0v = Xb[(size_t)(kbase + 0) * G_TOT + gcol];
            float x1v = Xb[(size_t)(kbase + 1) * G_TOT + gcol];
            float x2v = Xb[(size_t)(kbase + 2) * G_TOT + gcol];
            float x3v = Xb[(size_t)(kbase + 3) * G_TOT + gcol];
            half4 t; t[0] = (_Float16)x0v; t[1] = (_Float16)x1v;
            t[2] = (_Float16)x2v; t[3] = (_Float16)x3v;
            bf[kf] = t;
        }

#pragma unroll
        for (int l = 0; l < 4; ++l) {
            float4_ acc[4];
#pragma unroll
            for (int mt = 0; mt < 4; ++mt) { acc[mt][0]=0.f; acc[mt][1]=0.f; acc[mt][2]=0.f; acc[mt][3]=0.f; }
#pragma unroll
            for (int mt = 0; mt < 4; ++mt) {
#pragma unroll
                for (int kf = 0; kf < 4; ++kf) {
                    // A[m][k]: m = 16*mt + n, k = 16*kf + 4q + j  -> 4 contiguous f16
                    const _Float16* ap = &lwa[(l * 64 + (mt << 4) + n) * 68 + (kf << 4) + (q << 2)];
                    half4 a = *(const half4*)ap;
                    acc[mt] = __builtin_amdgcn_mfma_f32_16x16x16f16(a, bf[kf], acc[mt], 0, 0, 0);
                }
            }
            // epilogue: subtract exact bias, leaky-relu; D reg j == next B elem j (kf=mt)
#pragma unroll
            for (int mt = 0; mt < 4; ++mt) {
                float4_ bb = *(const float4_*)&biasb[l * 512 + (mt << 4) + (q << 2)];
                float y0 = acc[mt][0] - bb[0]; y0 = fmaxf(y0, 0.1f * y0);
                float y1 = acc[mt][1] - bb[1]; y1 = fmaxf(y1, 0.1f * y1);
                float y2 = acc[mt][2] - bb[2]; y2 = fmaxf(y2, 0.1f * y2);
                float y3 = acc[mt][3] - bb[3]; y3 = fmaxf(y3, 0.1f * y3);
                if (l == 3) {
                    rmax[mt][0] = fmaxf(rmax[mt][0], y0);
                    rmax[mt][1] = fmaxf(rmax[mt][1], y1);
                    rmax[mt][2] = fmaxf(rmax[mt][2], y2);
                    rmax[mt][3] = fmaxf(rmax[mt][3], y3);
                } else {
                    half4 t; t[0] = (_Float16)y0; t[1] = (_Float16)y1;
                    t[2] = (_Float16)y2; t[3] = (_Float16)y3;
                    bf[mt] = t;
                }
            }
        }
    }

    // reduce over the 16 column-lanes (bits 0..3 of lane id)
#pragma unroll
    for (int mt = 0; mt < 4; ++mt)
#pragma unroll
        for (int j = 0; j < 4; ++j) {
            float v = rmax[mt][j];
            v = fmaxf(v, __shfl_xor(v, 1, 64));
            v = fmaxf(v, __shfl_xor(v, 2, 64));
            v = fmaxf(v, __shfl_xor(v, 4, 64));
            v = fmaxf(v, __shfl_xor(v, 8, 64));
            rmax[mt][j] = v;
        }
    if (n == 0) {
#pragma unroll
        for (int mt = 0; mt < 4; ++mt)
#pragma unroll
            for (int j = 0; j < 4; ++j)
                blockmax[w][(mt << 4) + (q << 2) + j] = rmax[mt][j];
    }
    __syncthreads();
    if (tid < 64) {
        float v = fmaxf(fmaxf(blockmax[0][tid], blockmax[1][tid]),
                        fmaxf(blockmax[2][tid], blockmax[3][tid]));
        // order-preserving uint encoding for float atomicMax
        unsigned s = __float_as_uint(v);
        unsigned enc = (s & 0x80000000u) ? ~s : (s | 0x80000000u);
        atomicMax(&maxenc[b * 64 + tid], enc);
    }
}

__global__ void ge_final(const unsigned* __restrict__ maxenc, float* __restrict__ out)
{
    int i = threadIdx.x;
    if (i < 512) {
        unsigned u = maxenc[i];
        unsigned s = (u & 0x80000000u) ? (u ^ 0x80000000u) : ~u;
        out[i] = __uint_as_float(s);
    }
}

extern "C" void kernel_launch(void* const* d_in, const int* in_sizes, int n_in,
                              void* d_out, int out_size, void* d_ws, size_t ws_size,
                              hipStream_t stream) {
    const float* feat = (const float*)d_in[0];
    const float* W0 = (const float*)d_in[1];
    const float* W1 = (const float*)d_in[2];
    const float* W2 = (const float*)d_in[3];
    const float* W3 = (const float*)d_in[4];
    float* ws = (float*)d_ws;
    unsigned* maxenc = (unsigned*)(ws + 18432);

    ge_prep<<<1, 512, 0, stream>>>(feat, W0, W1, W2, W3, ws);
    ge_main<<<2048, 256, 0, stream>>>(feat, ws, ws + 16384, maxenc);
    ge_final<<<1, 512, 0, stream>>>(maxenc, (float*)d_out);
}